// Round 1
// baseline (328.143 us; speedup 1.0000x reference)
//
#include <hip/hip_runtime.h>

// DIMKT forward. B=512, S=200, E=128.
// Phase 1 (dimkt_prep): fold embedding tables through W1/W4/W5/W6 halves:
//   C1[1025][128], SD1[102][128](+b1), SD6[102][128], A4/A5/A6[2][128](+b)
// Phase 2 (dimkt_scan): 256 blocks x 512 thr; block owns 2 batch rows mapped to
//   MFMA M-rows {0,8}; 8 waves each own a 16-wide slice of E. Five 128x128
//   matmuls/step via mfma_f32_16x16x32_f16, weights resident in VGPR B-frags.
//   Activations staged in XOR-swizzled LDS (D-layout -> A-layout). Logit dot
//   fused; out[b][s] = sigmoid(dot(target_row, k_new)).

#define S_ 200
#define E_ 128

typedef float  float4v __attribute__((ext_vector_type(4)));
typedef _Float16 f16x8 __attribute__((ext_vector_type(8)));

__device__ __forceinline__ float fast_sigmoid(float x) {
  return __builtin_amdgcn_rcpf(1.f + __expf(-x));
}
__device__ __forceinline__ float fast_tanh(float x) {
  return 2.f * __builtin_amdgcn_rcpf(1.f + __expf(-2.f * x)) - 1.f;
}

__device__ __forceinline__ f16x8 cvt8(const float* __restrict__ p) {
  float4v a = *(const float4v*)p;
  float4v b = *(const float4v*)(p + 4);
  f16x8 r;
  r[0] = (_Float16)a[0]; r[1] = (_Float16)a[1];
  r[2] = (_Float16)a[2]; r[3] = (_Float16)a[3];
  r[4] = (_Float16)b[0]; r[5] = (_Float16)b[1];
  r[6] = (_Float16)b[2]; r[7] = (_Float16)b[3];
  return r;
}

// swizzled column offset within a 128-wide LDS row (16B-block XOR swizzle)
__device__ __forceinline__ int swz(int m, int col) {
  return (((col >> 3) ^ (m & 7)) << 3) | (col & 7);
}

// ---------------- phase 1: table precompute ----------------
// ws float offsets: C1=0 (131200), SD1=131200 (13056), SD6=144256 (13056),
//                   A4=157312, A5=157568, A6=157824  (total 158080 floats)
__global__ void dimkt_prep(const float* __restrict__ c_table,
                           const float* __restrict__ sd_table,
                           const float* __restrict__ a_table,
                           const float* __restrict__ W1, const float* __restrict__ b1,
                           const float* __restrict__ W4, const float* __restrict__ b4,
                           const float* __restrict__ W5, const float* __restrict__ b5,
                           const float* __restrict__ W6, const float* __restrict__ b6,
                           float* __restrict__ ws) {
  __shared__ __attribute__((aligned(16))) float src[E_];
  const int row = blockIdx.x;
  const int e = threadIdx.x;
  const float* srcp; const float* wbase; int wstride, woff;
  const float* bias; float* dst;
  if (row < 1025)      { srcp = c_table + row * E_;                 wbase = W1; wstride = 256; woff = 0;   bias = nullptr; dst = ws + row * E_; }
  else if (row < 1127) { int i = row - 1025; srcp = sd_table + i * E_; wbase = W1; wstride = 256; woff = 128; bias = b1;     dst = ws + 131200 + i * E_; }
  else if (row < 1229) { int i = row - 1127; srcp = sd_table + i * E_; wbase = W6; wstride = 384; woff = 256; bias = nullptr; dst = ws + 144256 + i * E_; }
  else if (row < 1231) { int i = row - 1229; srcp = a_table + i * E_;  wbase = W4; wstride = 256; woff = 128; bias = b4;     dst = ws + 157312 + i * E_; }
  else if (row < 1233) { int i = row - 1231; srcp = a_table + i * E_;  wbase = W5; wstride = 256; woff = 128; bias = b5;     dst = ws + 157568 + i * E_; }
  else                 { int i = row - 1233; srcp = a_table + i * E_;  wbase = W6; wstride = 384; woff = 128; bias = b6;     dst = ws + 157824 + i * E_; }
  src[e] = srcp[e];
  __syncthreads();
  const float4v* wr = (const float4v*)(wbase + e * wstride + woff);
  const float4v* sr = (const float4v*)src;
  float acc = bias ? bias[e] : 0.f;
  #pragma unroll 8
  for (int jj = 0; jj < 32; ++jj) {
    float4v wv = wr[jj], sv = sr[jj];
    acc += wv[0]*sv[0] + wv[1]*sv[1] + wv[2]*sv[2] + wv[3]*sv[3];
  }
  dst[e] = acc;
}

// ---------------- phase 2: sequential scan ----------------
__global__ __launch_bounds__(512, 2) void dimkt_scan(
    const int* __restrict__ c, const int* __restrict__ sd, const int* __restrict__ a,
    const int* __restrict__ cshft, const int* __restrict__ sdshft,
    const float* __restrict__ knowledge,
    const float* __restrict__ W2, const float* __restrict__ b2,
    const float* __restrict__ W3, const float* __restrict__ b3,
    const float* __restrict__ W4, const float* __restrict__ W5,
    const float* __restrict__ W6,
    const float* __restrict__ ws, float* __restrict__ out) {

  const float* __restrict__ C1  = ws;
  const float* __restrict__ SD1 = ws + 131200;
  const float* __restrict__ SD6 = ws + 144256;
  const float* __restrict__ A4  = ws + 157312;
  const float* __restrict__ A5  = ws + 157568;
  const float* __restrict__ A6  = ws + 157824;

  const int tid  = threadIdx.x;
  const int w    = tid >> 6;        // wave 0..7, owns E-slice [16w,16w+16)
  const int lane = tid & 63;
  const int l15  = lane & 15;
  const int q    = lane >> 4;       // quad 0..3
  const int e    = w * 16 + l15;    // this lane's output column
  const int j    = q >> 1;          // batch row within block (0,0,1,1)
  const int bj   = blockIdx.x * 2 + j;
  const int mrow = q << 2;          // D-layout row this quad owns (0,4,8,12)

  __shared__ __attribute__((aligned(16))) _Float16 st_qq[2048];
  __shared__ __attribute__((aligned(16))) _Float16 st_sdf[2048];
  __shared__ __attribute__((aligned(16))) _Float16 st_k[2048];
  __shared__ float red[2][8][2];

  for (int i = tid; i < 2048; i += 512) {
    st_qq[i] = (_Float16)0.f; st_sdf[i] = (_Float16)0.f; st_k[i] = (_Float16)0.f;
  }

  // Weight B-fragments: lane holds W[e][32t + 8q + 0..7] (B[k][n], n=l15 slice)
  f16x8 w2f[4], w3f[4], w4f[4], w5f[4], w6f[4];
  #pragma unroll
  for (int t = 0; t < 4; ++t) {
    const int ko = t * 32 + q * 8;
    w2f[t] = cvt8(W2 + e * 128 + ko);
    w3f[t] = cvt8(W3 + e * 128 + ko);
    w4f[t] = cvt8(W4 + e * 256 + ko);   // first 128 cols of W4
    w5f[t] = cvt8(W5 + e * 256 + ko);
    w6f[t] = cvt8(W6 + e * 384 + ko);
  }
  const float b2e = b2[e], b3e = b3[e];
  const float A4t0 = A4[e], A4t1 = A4[E_ + e];
  const float A5t0 = A5[e], A5t1 = A5[E_ + e];
  const float A6t0 = A6[e], A6t1 = A6[E_ + e];

  float kreg = knowledge[e];   // fp32 master state, row mrow / col e

  // step-0 gathers + step-1 indices (software pipeline depth: idx 2, gather 1)
  const int base = bj * S_;
  int ic = c[base], isd = sd[base], ia = a[base], ict = cshft[base], ist = sdshft[base];
  float inT  = C1[ic * E_ + e] + SD1[isd * E_ + e];
  float sd6v = SD6[isd * E_ + e];
  float a4v = ia ? A4t1 : A4t0;
  float a5v = ia ? A5t1 : A5t0;
  float a6v = ia ? A6t1 : A6t0;
  float tgt  = C1[ict * E_ + e] + SD1[ist * E_ + e];
  int nic = c[base + 1], nisd = sd[base + 1], nia = a[base + 1],
      nict = cshft[base + 1], nist = sdshft[base + 1];

  __syncthreads();                       // zero-init visible
  st_k[mrow * 128 + swz(mrow, e)] = (_Float16)kreg;
  __syncthreads();                       // k stage visible

  #pragma unroll 1
  for (int s = 0; s < S_; ++s) {
    // A-frags of k (staged at end of previous step) — read early, used late
    f16x8 kf[4];
    #pragma unroll
    for (int t = 0; t < 4; ++t)
      kf[t] = *(const f16x8*)&st_k[l15 * 128 + (((4 * t + q) ^ (l15 & 7)) << 3)];

    float qq = kreg - inT;
    st_qq[mrow * 128 + swz(mrow, e)] = (_Float16)qq;
    __syncthreads();   // B1: qq staged (also: kf reads complete before st_k rewrite)

    f16x8 qf[4];
    #pragma unroll
    for (int t = 0; t < 4; ++t)
      qf[t] = *(const f16x8*)&st_qq[l15 * 128 + (((4 * t + q) ^ (l15 & 7)) << 3)];

    float4v acc2 = {b2e, b2e, b2e, b2e};
    float4v acc3 = {b3e, b3e, b3e, b3e};
    #pragma unroll
    for (int t = 0; t < 4; ++t) {
      acc2 = __builtin_amdgcn_mfma_f32_16x16x32_f16(qf[t], w2f[t], acc2, 0, 0, 0);
      acc3 = __builtin_amdgcn_mfma_f32_16x16x32_f16(qf[t], w3f[t], acc3, 0, 0, 0);
    }

    // prefetch next step (hide L2 gather latency under MFMA/transcendentals)
    float ninT = C1[nic * E_ + e] + SD1[nisd * E_ + e];
    float nsd6 = SD6[nisd * E_ + e];
    float na4 = nia ? A4t1 : A4t0;
    float na5 = nia ? A5t1 : A5t0;
    float na6 = nia ? A6t1 : A6t0;
    float ntg  = C1[nict * E_ + e] + SD1[nist * E_ + e];
    int s2 = (s + 2 < S_) ? (s + 2) : (S_ - 1);
    int pi = bj * S_ + s2;
    int tic = c[pi], tisd = sd[pi], tia = a[pi], tict = cshft[pi], tist = sdshft[pi];

    float g2   = fast_sigmoid(acc2[0]);
    float th3  = fast_tanh(acc3[0]);
    float sdfv = g2 * th3;
    st_sdf[mrow * 128 + swz(mrow, e)] = (_Float16)sdfv;
    __syncthreads();   // B2: sdf staged

    // W6 on k first (kf ready since step start)
    float bias6 = a6v + sd6v;
    float4v acc6 = {bias6, bias6, bias6, bias6};
    #pragma unroll
    for (int t = 0; t < 4; ++t)
      acc6 = __builtin_amdgcn_mfma_f32_16x16x32_f16(kf[t], w6f[t], acc6, 0, 0, 0);

    f16x8 sf[4];
    #pragma unroll
    for (int t = 0; t < 4; ++t)
      sf[t] = *(const f16x8*)&st_sdf[l15 * 128 + (((4 * t + q) ^ (l15 & 7)) << 3)];

    float4v acc4 = {a4v, a4v, a4v, a4v};
    float4v acc5 = {a5v, a5v, a5v, a5v};
    #pragma unroll
    for (int t = 0; t < 4; ++t) {
      acc4 = __builtin_amdgcn_mfma_f32_16x16x32_f16(sf[t], w4f[t], acc4, 0, 0, 0);
      acc5 = __builtin_amdgcn_mfma_f32_16x16x32_f16(sf[t], w5f[t], acc5, 0, 0, 0);
    }

    float g4   = fast_sigmoid(acc4[0]);
    float th5  = fast_tanh(acc5[0]);
    float pka  = g4 * th5;
    float g6   = fast_sigmoid(acc6[0]);
    float knew = pka + g6 * (kreg - pka);
    kreg = knew;
    st_k[mrow * 128 + swz(mrow, e)] = (_Float16)knew;

    // fused logit: dot(target_row, k_new) over e
    float p = tgt * knew;
    p += __shfl_xor(p, 1);
    p += __shfl_xor(p, 2);
    p += __shfl_xor(p, 4);
    p += __shfl_xor(p, 8);
    if (l15 == 0 && (q & 1) == 0) red[s & 1][w][j] = p;

    inT = ninT; sd6v = nsd6; a4v = na4; a5v = na5; a6v = na6; tgt = ntg;
    nic = tic; nisd = tisd; nia = tia; nict = tict; nist = tist;

    __syncthreads();   // B3: k stage + reduction partials visible

    if (tid == 0 || tid == 32) {
      const int jj = tid >> 5;
      float logit = 0.f;
      #pragma unroll
      for (int x = 0; x < 8; ++x) logit += red[s & 1][x][jj];
      out[(blockIdx.x * 2 + jj) * S_ + s] = fast_sigmoid(logit);
    }
  }
}

extern "C" void kernel_launch(void* const* d_in, const int* in_sizes, int n_in,
                              void* d_out, int out_size, void* d_ws, size_t ws_size,
                              hipStream_t stream) {
  const int*   c         = (const int*)  d_in[0];
  const int*   sd        = (const int*)  d_in[1];
  const int*   a         = (const int*)  d_in[2];
  const int*   cshft     = (const int*)  d_in[3];
  const int*   sdshft    = (const int*)  d_in[4];
  const float* c_table   = (const float*)d_in[5];
  const float* sd_table  = (const float*)d_in[6];
  const float* a_table   = (const float*)d_in[7];
  const float* knowledge = (const float*)d_in[8];
  const float* W1 = (const float*)d_in[9];  const float* b1 = (const float*)d_in[10];
  const float* W2 = (const float*)d_in[11]; const float* b2 = (const float*)d_in[12];
  const float* W3 = (const float*)d_in[13]; const float* b3 = (const float*)d_in[14];
  const float* W4 = (const float*)d_in[15]; const float* b4 = (const float*)d_in[16];
  const float* W5 = (const float*)d_in[17]; const float* b5 = (const float*)d_in[18];
  const float* W6 = (const float*)d_in[19]; const float* b6 = (const float*)d_in[20];
  float* ws  = (float*)d_ws;
  float* out = (float*)d_out;
  (void)in_sizes; (void)n_in; (void)out_size; (void)ws_size;

  dimkt_prep<<<1235, 128, 0, stream>>>(c_table, sd_table, a_table,
                                       W1, b1, W4, b4, W5, b5, W6, b6, ws);
  dimkt_scan<<<256, 512, 0, stream>>>(c, sd, a, cshft, sdshft, knowledge,
                                      W2, b2, W3, b3, W4, W5, W6, ws, out);
}

// Round 2
// 318.875 us; speedup vs baseline: 1.0291x; 1.0291x over previous
//
#include <hip/hip_runtime.h>

// DIMKT forward. B=512, S=200, E=128.
// prep_c1:  C1[1025][128] = c_table @ W1[:, :E].T            (8 rows/block, W in VGPRs)
// prep_tail: SD1[102](+b1), SD6[102], A4/A5/A6[2] (+biases)  (1 row/block)
// dimkt_scan: 256 blocks x 512 thr, 2 batch rows/block. Per step TWO stages:
//   stage1 A-tile packs qq in rows {0,8} and k in rows {4,12} -> one frag set
//   feeds W2, W3 (qq rows) and W6 (k rows). stage2 A = sdf rows {0,8}.
//   2 barriers/step, padded LDS rows (stride 136 halves) for balanced banks.

#define S_ 200
#define E_ 128
#define SH 136   // halves per LDS row (+8 pad -> balanced banks, 16B aligned)

typedef float  float4v __attribute__((ext_vector_type(4)));
typedef _Float16 f16x8 __attribute__((ext_vector_type(8)));

__device__ __forceinline__ float fast_sigmoid(float x) {
  return __builtin_amdgcn_rcpf(1.f + __expf(-x));
}
__device__ __forceinline__ float fast_tanh(float x) {
  return 2.f * __builtin_amdgcn_rcpf(1.f + __expf(-2.f * x)) - 1.f;
}

__device__ __forceinline__ f16x8 cvt8(const float* __restrict__ p) {
  float4v a = *(const float4v*)p;
  float4v b = *(const float4v*)(p + 4);
  f16x8 r;
  r[0] = (_Float16)a[0]; r[1] = (_Float16)a[1];
  r[2] = (_Float16)a[2]; r[3] = (_Float16)a[3];
  r[4] = (_Float16)b[0]; r[5] = (_Float16)b[1];
  r[6] = (_Float16)b[2]; r[7] = (_Float16)b[3];
  return r;
}

// ---------------- prep A: C1 table (1025 rows) ----------------
__global__ void dimkt_prep_c1(const float* __restrict__ c_table,
                              const float* __restrict__ W1,
                              float* __restrict__ ws) {
  __shared__ __attribute__((aligned(16))) float src[8][E_];
  const int tid = threadIdx.x;          // 256
  const int e = tid & 127, h = tid >> 7;
  const int r0 = blockIdx.x * 8;
  for (int g = h; g < 8; g += 2) {
    int r = r0 + g; if (r > 1024) r = 1024;
    src[g][e] = c_table[r * E_ + e];
  }
  float4v wreg[32];
  const float4v* wr = (const float4v*)(W1 + e * 256);   // first 128 cols of row e
  #pragma unroll
  for (int i = 0; i < 32; ++i) wreg[i] = wr[i];
  __syncthreads();
  float acc[4] = {0.f, 0.f, 0.f, 0.f};
  #pragma unroll 4
  for (int i = 0; i < 32; ++i) {
    float4v wv = wreg[i];
    #pragma unroll
    for (int g = 0; g < 4; ++g) {
      float4v sv = *(const float4v*)&src[h * 4 + g][i * 4];
      acc[g] += wv[0]*sv[0] + wv[1]*sv[1] + wv[2]*sv[2] + wv[3]*sv[3];
    }
  }
  #pragma unroll
  for (int g = 0; g < 4; ++g) {
    int r = r0 + h * 4 + g;
    if (r <= 1024) ws[r * E_ + e] = acc[g];
  }
}

// ---------------- prep B: small tables (210 rows) ----------------
// ws float offsets: C1=0 (131200), SD1=131200, SD6=144256, A4=157312,
//                   A5=157568, A6=157824
__global__ void dimkt_prep_tail(const float* __restrict__ sd_table,
                                const float* __restrict__ a_table,
                                const float* __restrict__ W1, const float* __restrict__ b1,
                                const float* __restrict__ W4, const float* __restrict__ b4,
                                const float* __restrict__ W5, const float* __restrict__ b5,
                                const float* __restrict__ W6, const float* __restrict__ b6,
                                float* __restrict__ ws) {
  __shared__ __attribute__((aligned(16))) float src[E_];
  const int row = blockIdx.x;
  const int e = threadIdx.x;
  const float* srcp; const float* wbase; int wstride, woff;
  const float* bias; float* dst;
  if (row < 102)       {                 srcp = sd_table + row * E_;    wbase = W1; wstride = 256; woff = 128; bias = b1;     dst = ws + 131200 + row * E_; }
  else if (row < 204)  { int i = row - 102; srcp = sd_table + i * E_;   wbase = W6; wstride = 384; woff = 256; bias = nullptr; dst = ws + 144256 + i * E_; }
  else if (row < 206)  { int i = row - 204; srcp = a_table + i * E_;    wbase = W4; wstride = 256; woff = 128; bias = b4;     dst = ws + 157312 + i * E_; }
  else if (row < 208)  { int i = row - 206; srcp = a_table + i * E_;    wbase = W5; wstride = 256; woff = 128; bias = b5;     dst = ws + 157568 + i * E_; }
  else                 { int i = row - 208; srcp = a_table + i * E_;    wbase = W6; wstride = 384; woff = 128; bias = b6;     dst = ws + 157824 + i * E_; }
  src[e] = srcp[e];
  __syncthreads();
  const float4v* wr = (const float4v*)(wbase + e * wstride + woff);
  const float4v* sr = (const float4v*)src;
  float acc = bias ? bias[e] : 0.f;
  #pragma unroll 8
  for (int jj = 0; jj < 32; ++jj) {
    float4v wv = wr[jj], sv = sr[jj];
    acc += wv[0]*sv[0] + wv[1]*sv[1] + wv[2]*sv[2] + wv[3]*sv[3];
  }
  dst[e] = acc;
}

// ---------------- the scan ----------------
__global__ __launch_bounds__(512, 2) void dimkt_scan(
    const int* __restrict__ c, const int* __restrict__ sd, const int* __restrict__ a,
    const int* __restrict__ cshft, const int* __restrict__ sdshft,
    const float* __restrict__ knowledge,
    const float* __restrict__ W2, const float* __restrict__ b2,
    const float* __restrict__ W3, const float* __restrict__ b3,
    const float* __restrict__ W4, const float* __restrict__ W5,
    const float* __restrict__ W6,
    const float* __restrict__ ws, float* __restrict__ out) {

  const float* __restrict__ C1  = ws;
  const float* __restrict__ SD1 = ws + 131200;
  const float* __restrict__ SD6 = ws + 144256;
  const float* __restrict__ A4  = ws + 157312;
  const float* __restrict__ A5  = ws + 157568;
  const float* __restrict__ A6  = ws + 157824;

  const int tid  = threadIdx.x;
  const int w    = tid >> 6;        // wave 0..7 -> E-slice [16w, 16w+16)
  const int lane = tid & 63;
  const int l15  = lane & 15;
  const int q    = lane >> 4;       // quad 0..3
  const int e    = w * 16 + l15;    // output column this lane owns
  const int j    = q >> 1;          // batch row within block
  const int bj   = blockIdx.x * 2 + j;
  const int mrow = q << 2;          // A/D tile row this quad owns (0,4,8,12)
  // rows 0,8: qq / sdf (batch 0,1); rows 4,12: k (batch 0,1)

  __shared__ __attribute__((aligned(16))) _Float16 A1[16 * SH];
  __shared__ __attribute__((aligned(16))) _Float16 A2[16 * SH];
  __shared__ float red[8][2];

  for (int i = tid; i < 16 * SH; i += 512) {
    A1[i] = (_Float16)0.f; A2[i] = (_Float16)0.f;
  }

  // Weight B-fragments: lane holds W[e][32t + 8q + 0..7]
  f16x8 w2f[4], w3f[4], w4f[4], w5f[4], w6f[4];
  #pragma unroll
  for (int t = 0; t < 4; ++t) {
    const int ko = t * 32 + q * 8;
    w2f[t] = cvt8(W2 + e * 128 + ko);
    w3f[t] = cvt8(W3 + e * 128 + ko);
    w4f[t] = cvt8(W4 + e * 256 + ko);   // first E cols
    w5f[t] = cvt8(W5 + e * 256 + ko);
    w6f[t] = cvt8(W6 + e * 384 + ko);   // k third of W6
  }
  const float b2e = b2[e], b3e = b3[e];
  const float A4t0 = A4[e], A4t1 = A4[E_ + e];
  const float A5t0 = A5[e], A5t1 = A5[E_ + e];
  const float A6t0 = A6[e], A6t1 = A6[E_ + e];

  float kreg = knowledge[e];

  const int base = bj * S_;
  int ic = c[base], isd = sd[base], ia = a[base], ict = cshft[base], ist = sdshft[base];
  float inT  = C1[ic * E_ + e] + SD1[isd * E_ + e];
  float sd6v = SD6[isd * E_ + e];
  float a4v = ia ? A4t1 : A4t0;
  float a5v = ia ? A5t1 : A5t0;
  float a6v = ia ? A6t1 : A6t0;
  float tgt  = C1[ict * E_ + e] + SD1[ist * E_ + e];
  int nic = c[base + 1], nisd = sd[base + 1], nia = a[base + 1],
      nict = cshft[base + 1], nist = sdshft[base + 1];

  __syncthreads();                         // LDS zero-init visible
  A1[mrow * SH + e] = (_Float16)((q & 1) ? kreg : (kreg - inT));
  __syncthreads();                         // initial A1 staged

  #pragma unroll 1
  for (int s = 0; s < S_; ++s) {
    // ---- stage 1: one frag set serves W2, W3 (qq rows) and W6 (k rows) ----
    f16x8 f[4];
    #pragma unroll
    for (int t = 0; t < 4; ++t)
      f[t] = *(const f16x8*)&A1[l15 * SH + ((4 * t + q) << 3)];

    // prefetch next step's gathers early (L2-latency hiding)
    float ninT = C1[nic * E_ + e] + SD1[nisd * E_ + e];
    float nsd6 = SD6[nisd * E_ + e];
    float na4 = nia ? A4t1 : A4t0;
    float na5 = nia ? A5t1 : A5t0;
    float na6 = nia ? A6t1 : A6t0;
    float ntg  = C1[nict * E_ + e] + SD1[nist * E_ + e];
    int s2 = (s + 2 < S_) ? (s + 2) : (S_ - 1);
    int pi = bj * S_ + s2;
    int tic = c[pi], tisd = sd[pi], tia = a[pi], tict = cshft[pi], tist = sdshft[pi];

    const float bias6 = a6v + sd6v;
    float4v a2a = {b2e, b2e, b2e, b2e},       a2b = {0.f, 0.f, 0.f, 0.f};
    float4v a3a = {b3e, b3e, b3e, b3e},       a3b = {0.f, 0.f, 0.f, 0.f};
    float4v a6a = {bias6, bias6, bias6, bias6}, a6b = {0.f, 0.f, 0.f, 0.f};
    a2a = __builtin_amdgcn_mfma_f32_16x16x32_f16(f[0], w2f[0], a2a, 0, 0, 0);
    a3a = __builtin_amdgcn_mfma_f32_16x16x32_f16(f[0], w3f[0], a3a, 0, 0, 0);
    a6a = __builtin_amdgcn_mfma_f32_16x16x32_f16(f[0], w6f[0], a6a, 0, 0, 0);
    a2b = __builtin_amdgcn_mfma_f32_16x16x32_f16(f[1], w2f[1], a2b, 0, 0, 0);
    a3b = __builtin_amdgcn_mfma_f32_16x16x32_f16(f[1], w3f[1], a3b, 0, 0, 0);
    a6b = __builtin_amdgcn_mfma_f32_16x16x32_f16(f[1], w6f[1], a6b, 0, 0, 0);
    a2a = __builtin_amdgcn_mfma_f32_16x16x32_f16(f[2], w2f[2], a2a, 0, 0, 0);
    a3a = __builtin_amdgcn_mfma_f32_16x16x32_f16(f[2], w3f[2], a3a, 0, 0, 0);
    a6a = __builtin_amdgcn_mfma_f32_16x16x32_f16(f[2], w6f[2], a6a, 0, 0, 0);
    a2b = __builtin_amdgcn_mfma_f32_16x16x32_f16(f[3], w2f[3], a2b, 0, 0, 0);
    a3b = __builtin_amdgcn_mfma_f32_16x16x32_f16(f[3], w3f[3], a3b, 0, 0, 0);
    a6b = __builtin_amdgcn_mfma_f32_16x16x32_f16(f[3], w6f[3], a6b, 0, 0, 0);
    const float v2 = a2a[0] + a2b[0];
    const float v3 = a3a[0] + a3b[0];
    const float v6 = a6a[0] + a6b[0];

    const float g2  = fast_sigmoid(v2);       // real in quads 0,2
    const float th3 = fast_tanh(v3);
    const float sdfv = g2 * th3;
    const float g6  = fast_sigmoid(v6);       // real in quads 1,3
    A2[mrow * SH + e] = (_Float16)sdfv;       // quads 1,3 write garbage rows 4,12 (unused)
    __syncthreads();                          // B1: sdf staged

    // ---- stage 2: W4, W5 on sdf ----
    f16x8 sf[4];
    #pragma unroll
    for (int t = 0; t < 4; ++t)
      sf[t] = *(const f16x8*)&A2[l15 * SH + ((4 * t + q) << 3)];

    float4v a4a = {a4v, a4v, a4v, a4v}, a4b = {0.f, 0.f, 0.f, 0.f};
    float4v a5a = {a5v, a5v, a5v, a5v}, a5b = {0.f, 0.f, 0.f, 0.f};
    a4a = __builtin_amdgcn_mfma_f32_16x16x32_f16(sf[0], w4f[0], a4a, 0, 0, 0);
    a5a = __builtin_amdgcn_mfma_f32_16x16x32_f16(sf[0], w5f[0], a5a, 0, 0, 0);
    a4b = __builtin_amdgcn_mfma_f32_16x16x32_f16(sf[1], w4f[1], a4b, 0, 0, 0);
    a5b = __builtin_amdgcn_mfma_f32_16x16x32_f16(sf[1], w5f[1], a5b, 0, 0, 0);
    a4a = __builtin_amdgcn_mfma_f32_16x16x32_f16(sf[2], w4f[2], a4a, 0, 0, 0);
    a5a = __builtin_amdgcn_mfma_f32_16x16x32_f16(sf[2], w5f[2], a5a, 0, 0, 0);
    a4b = __builtin_amdgcn_mfma_f32_16x16x32_f16(sf[3], w4f[3], a4b, 0, 0, 0);
    a5b = __builtin_amdgcn_mfma_f32_16x16x32_f16(sf[3], w5f[3], a5b, 0, 0, 0);
    const float v4 = a4a[0] + a4b[0];
    const float v5 = a5a[0] + a5b[0];

    const float pka = fast_sigmoid(v4) * fast_tanh(v5);  // real in quads 0,2
    // exchange pka (even quads) <-> g6 (odd quads) within quad pair
    const float send = (q & 1) ? g6 : pka;
    const float recv = __shfl_xor(send, 16);
    const float gg6  = (q & 1) ? g6 : recv;
    const float ppka = (q & 1) ? recv : pka;
    const float knew = ppka + gg6 * (kreg - ppka);
    kreg = knew;
    // stage next step's A1: qq' in even-quad rows, k' in odd-quad rows
    A1[mrow * SH + e] = (_Float16)((q & 1) ? knew : (knew - ninT));

    // fused logit: dot(target, knew) over e
    float p = tgt * knew;
    p += __shfl_xor(p, 1);
    p += __shfl_xor(p, 2);
    p += __shfl_xor(p, 4);
    p += __shfl_xor(p, 8);
    if (l15 == 0 && !(q & 1)) red[w][j] = p;

    inT = ninT; sd6v = nsd6; a4v = na4; a5v = na5; a6v = na6; tgt = ntg;
    nic = tic; nisd = tisd; nia = tia; nict = tict; nist = tist;

    __syncthreads();                          // B2: A1' + red visible

    if (tid == 0 || tid == 32) {
      const int jj = tid >> 5;
      float logit = 0.f;
      #pragma unroll
      for (int x = 0; x < 8; ++x) logit += red[x][jj];
      out[(blockIdx.x * 2 + jj) * S_ + s] = fast_sigmoid(logit);
    }
  }
}

extern "C" void kernel_launch(void* const* d_in, const int* in_sizes, int n_in,
                              void* d_out, int out_size, void* d_ws, size_t ws_size,
                              hipStream_t stream) {
  const int*   c         = (const int*)  d_in[0];
  const int*   sd        = (const int*)  d_in[1];
  const int*   a         = (const int*)  d_in[2];
  const int*   cshft     = (const int*)  d_in[3];
  const int*   sdshft    = (const int*)  d_in[4];
  const float* c_table   = (const float*)d_in[5];
  const float* sd_table  = (const float*)d_in[6];
  const float* a_table   = (const float*)d_in[7];
  const float* knowledge = (const float*)d_in[8];
  const float* W1 = (const float*)d_in[9];  const float* b1 = (const float*)d_in[10];
  const float* W2 = (const float*)d_in[11]; const float* b2 = (const float*)d_in[12];
  const float* W3 = (const float*)d_in[13]; const float* b3 = (const float*)d_in[14];
  const float* W4 = (const float*)d_in[15]; const float* b4 = (const float*)d_in[16];
  const float* W5 = (const float*)d_in[17]; const float* b5 = (const float*)d_in[18];
  const float* W6 = (const float*)d_in[19]; const float* b6 = (const float*)d_in[20];
  float* ws  = (float*)d_ws;
  float* out = (float*)d_out;
  (void)in_sizes; (void)n_in; (void)out_size; (void)ws_size;

  dimkt_prep_c1<<<129, 256, 0, stream>>>(c_table, W1, ws);
  dimkt_prep_tail<<<210, 128, 0, stream>>>(sd_table, a_table,
                                           W1, b1, W4, b4, W5, b5, W6, b6, ws);
  dimkt_scan<<<256, 512, 0, stream>>>(c, sd, a, cshft, sdshft, knowledge,
                                      W2, b2, W3, b3, W4, W5, W6, ws, out);
}

// Round 3
// 277.563 us; speedup vs baseline: 1.1822x; 1.1488x over previous
//
#include <hip/hip_runtime.h>

// DIMKT forward. B=512, S=200, E=128.
// dimkt_prep: one coalesced kernel; folds embedding tables through W halves:
//   C1[1025](W1a), SD1[102](W1b+b1), SD6[102](W6c), A4/A5/A6[2](+biases).
// dimkt_scan: 256 blocks x 512 thr, 2 batch rows/block, 8 waves x 16-col slice.
//   Stage1 A-tile: qq rows {0,8}, k rows {4,12} -> one frag set feeds W2,W3,W6.
//   Stage2 A-tile: sdf rows {0,8}. Weights resident as VGPR B-frags.
//   Rotate-store swizzle (col += 16*(row>>2)) -> conflict-free LDS writes.
//   Persistent accumulators: only reg0 re-biased per step (garbage rows stale).
//   DPP row_shr reduction for the fused logit dot.

#define S_ 200
#define E_ 128
#define RS 136   // halves per LDS row (17*8 -> balanced read banks, 16B-aligned)

typedef float  float4v __attribute__((ext_vector_type(4)));
typedef _Float16 f16x8 __attribute__((ext_vector_type(8)));

__device__ __forceinline__ float fast_sigmoid(float x) {
  return __builtin_amdgcn_rcpf(1.f + __expf(-x));
}
__device__ __forceinline__ float fast_tanh(float x) {
  return 2.f * __builtin_amdgcn_rcpf(1.f + __expf(-2.f * x)) - 1.f;
}

// x + row_shr:<ctrl> shifted x (zeros shifted in); sum lands in lane15 of each 16-row
#define DPP_ADD(x, ctrl) \
  ((x) + __builtin_bit_cast(float, __builtin_amdgcn_update_dpp( \
       0, __builtin_bit_cast(int, (x)), (ctrl), 0xf, 0xf, true)))

__device__ __forceinline__ f16x8 cvt8(const float* __restrict__ p) {
  float4v a = *(const float4v*)p;
  float4v b = *(const float4v*)(p + 4);
  f16x8 r;
  r[0] = (_Float16)a[0]; r[1] = (_Float16)a[1];
  r[2] = (_Float16)a[2]; r[3] = (_Float16)a[3];
  r[4] = (_Float16)b[0]; r[5] = (_Float16)b[1];
  r[6] = (_Float16)b[2]; r[7] = (_Float16)b[3];
  return r;
}

// ---------------- prep: all 1235 table rows, coalesced W loads ----------------
// ws float offsets: C1=0 (131200), SD1=131200, SD6=144256, A4=157312,
//                   A5=157568, A6=157824
__global__ __launch_bounds__(128) void dimkt_prep(
    const float* __restrict__ c_table, const float* __restrict__ sd_table,
    const float* __restrict__ a_table,
    const float* __restrict__ W1, const float* __restrict__ b1,
    const float* __restrict__ W4, const float* __restrict__ b4,
    const float* __restrict__ W5, const float* __restrict__ b5,
    const float* __restrict__ W6, const float* __restrict__ b6,
    float* __restrict__ ws) {
  __shared__ float s_src[E_];
  __shared__ float s_w[E_][33];
  const int row = blockIdx.x;
  const int t = threadIdx.x;
  const float* srcp; const float* wbase; int wstride, woff;
  const float* bias; float* dst;
  if (row < 1025)      {                  srcp = c_table + row * E_; wbase = W1; wstride = 256; woff = 0;   bias = nullptr; dst = ws + row * E_; }
  else if (row < 1127) { int i = row-1025; srcp = sd_table + i * E_; wbase = W1; wstride = 256; woff = 128; bias = b1;     dst = ws + 131200 + i * E_; }
  else if (row < 1229) { int i = row-1127; srcp = sd_table + i * E_; wbase = W6; wstride = 384; woff = 256; bias = nullptr; dst = ws + 144256 + i * E_; }
  else if (row < 1231) { int i = row-1229; srcp = a_table + i * E_;  wbase = W4; wstride = 256; woff = 128; bias = b4;     dst = ws + 157312 + i * E_; }
  else if (row < 1233) { int i = row-1231; srcp = a_table + i * E_;  wbase = W5; wstride = 256; woff = 128; bias = b5;     dst = ws + 157568 + i * E_; }
  else                 { int i = row-1233; srcp = a_table + i * E_;  wbase = W6; wstride = 384; woff = 128; bias = b6;     dst = ws + 157824 + i * E_; }
  s_src[t] = srcp[t];
  float acc = bias ? bias[t] : 0.f;
  for (int k0 = 0; k0 < 128; k0 += 32) {
    __syncthreads();                      // protect s_src (first) / s_w reuse
    const int jj = t & 31, eb = t >> 5;
    #pragma unroll 8
    for (int i = 0; i < 32; ++i) {
      int ee = i * 4 + eb;
      s_w[ee][jj] = wbase[ee * wstride + woff + k0 + jj];   // coalesced 32-lane rows
    }
    __syncthreads();
    #pragma unroll 8
    for (int kk = 0; kk < 32; ++kk)
      acc += s_w[t][kk] * s_src[k0 + kk];
  }
  dst[t] = acc;
}

// ---------------- the scan ----------------
__global__ __launch_bounds__(512, 2) void dimkt_scan(
    const int* __restrict__ c, const int* __restrict__ sd, const int* __restrict__ a,
    const int* __restrict__ cshft, const int* __restrict__ sdshft,
    const float* __restrict__ knowledge,
    const float* __restrict__ W2, const float* __restrict__ b2,
    const float* __restrict__ W3, const float* __restrict__ b3,
    const float* __restrict__ W4, const float* __restrict__ W5,
    const float* __restrict__ W6,
    const float* __restrict__ ws, float* __restrict__ out) {

  const float* __restrict__ C1  = ws;
  const float* __restrict__ SD1 = ws + 131200;
  const float* __restrict__ SD6 = ws + 144256;
  const float* __restrict__ A4  = ws + 157312;
  const float* __restrict__ A5  = ws + 157568;
  const float* __restrict__ A6  = ws + 157824;

  const int tid  = threadIdx.x;
  const int w    = tid >> 6;        // wave 0..7 -> E-slice [16w, 16w+16)
  const int lane = tid & 63;
  const int l15  = lane & 15;
  const int q    = lane >> 4;       // quad 0..3
  const int qodd = q & 1;
  const int e    = w * 16 + l15;    // output column this lane owns
  const int j    = q >> 1;          // batch row within block
  const int bj   = blockIdx.x * 2 + j;
  const int mrow = q << 2;          // A/D tile row this quad owns (0,4,8,12)
  // rows 0,8: qq / sdf (batch 0,1); rows 4,12: k (batch 0,1)

  __shared__ __attribute__((aligned(16))) _Float16 A1[16 * RS];
  __shared__ __attribute__((aligned(16))) _Float16 A2[16 * RS];
  __shared__ float red[8][2];

  for (int i = tid; i < 16 * RS; i += 512) { A1[i] = (_Float16)0.f; A2[i] = (_Float16)0.f; }

  // rotate-store swizzle: physical col = (logical col + 16*(row>>2)) & 127
  const int st_off = mrow * RS + ((e + (q << 4)) & 127);
  int rdt[4];
  #pragma unroll
  for (int t = 0; t < 4; ++t)
    rdt[t] = l15 * RS + ((((4 * t + q) << 3) + ((l15 >> 2) << 4)) & 127);

  // Weight B-fragments: lane holds W[e][32t + 8q + 0..7]
  f16x8 w2f[4], w3f[4], w4f[4], w5f[4], w6f[4];
  #pragma unroll
  for (int t = 0; t < 4; ++t) {
    const int ko = t * 32 + q * 8;
    w2f[t] = cvt8(W2 + e * 128 + ko);
    w3f[t] = cvt8(W3 + e * 128 + ko);
    w4f[t] = cvt8(W4 + e * 256 + ko);   // first E cols
    w5f[t] = cvt8(W5 + e * 256 + ko);
    w6f[t] = cvt8(W6 + e * 384 + ko);   // k third of W6
  }
  const float b2e = b2[e], b3e = b3[e];
  const float A4t0 = A4[e], A4t1 = A4[E_ + e];
  const float A5t0 = A5[e], A5t1 = A5[E_ + e];
  const float A6t0 = A6[e], A6t1 = A6[E_ + e];

  float kreg = knowledge[e];

  const int base = bj * S_;
  int ic = c[base], isd = sd[base], ia = a[base], ict = cshft[base], ist = sdshft[base];
  float inT  = C1[ic * E_ + e] + SD1[isd * E_ + e];
  float sd6v = SD6[isd * E_ + e];
  float a4v = ia ? A4t1 : A4t0;
  float a5v = ia ? A5t1 : A5t0;
  float a6v = ia ? A6t1 : A6t0;
  float tgt  = C1[ict * E_ + e] + SD1[ist * E_ + e];
  int nic = c[base + 1], nisd = sd[base + 1], nia = a[base + 1],
      nict = cshft[base + 1], nist = sdshft[base + 1];

  __syncthreads();                         // LDS zero-init visible
  A1[st_off] = (_Float16)(qodd ? kreg : (kreg - inT));
  __syncthreads();                         // initial A1 staged

  // persistent accumulators: regs 1-3 carry harmless stale values (their A-rows
  // are LDS zeros, so D[1..3] = 0*B + C = constant); only reg0 is re-biased.
  float4v acc2{0.f,0.f,0.f,0.f}, acc3{0.f,0.f,0.f,0.f}, acc6{0.f,0.f,0.f,0.f};
  float4v acc4{0.f,0.f,0.f,0.f}, acc5{0.f,0.f,0.f,0.f};

  #pragma unroll 1
  for (int s = 0; s < S_; ++s) {
    // ---- stage 1: one frag set serves W2, W3 (qq rows) and W6 (k rows) ----
    f16x8 f0 = *(const f16x8*)&A1[rdt[0]];
    f16x8 f1 = *(const f16x8*)&A1[rdt[1]];
    f16x8 f2 = *(const f16x8*)&A1[rdt[2]];
    f16x8 f3 = *(const f16x8*)&A1[rdt[3]];

    // prefetch next step's gathers early (L2-latency hiding)
    float ninT = C1[nic * E_ + e] + SD1[nisd * E_ + e];
    float nsd6 = SD6[nisd * E_ + e];
    float na4 = nia ? A4t1 : A4t0;
    float na5 = nia ? A5t1 : A5t0;
    float na6 = nia ? A6t1 : A6t0;
    float ntg  = C1[nict * E_ + e] + SD1[nist * E_ + e];

    acc2[0] = b2e;
    acc3[0] = b3e;
    acc6[0] = a6v + sd6v;
    acc2 = __builtin_amdgcn_mfma_f32_16x16x32_f16(f0, w2f[0], acc2, 0, 0, 0);
    acc3 = __builtin_amdgcn_mfma_f32_16x16x32_f16(f0, w3f[0], acc3, 0, 0, 0);
    acc6 = __builtin_amdgcn_mfma_f32_16x16x32_f16(f0, w6f[0], acc6, 0, 0, 0);
    acc2 = __builtin_amdgcn_mfma_f32_16x16x32_f16(f1, w2f[1], acc2, 0, 0, 0);
    acc3 = __builtin_amdgcn_mfma_f32_16x16x32_f16(f1, w3f[1], acc3, 0, 0, 0);
    acc6 = __builtin_amdgcn_mfma_f32_16x16x32_f16(f1, w6f[1], acc6, 0, 0, 0);
    acc2 = __builtin_amdgcn_mfma_f32_16x16x32_f16(f2, w2f[2], acc2, 0, 0, 0);
    acc3 = __builtin_amdgcn_mfma_f32_16x16x32_f16(f2, w3f[2], acc3, 0, 0, 0);
    acc6 = __builtin_amdgcn_mfma_f32_16x16x32_f16(f2, w6f[2], acc6, 0, 0, 0);
    acc2 = __builtin_amdgcn_mfma_f32_16x16x32_f16(f3, w2f[3], acc2, 0, 0, 0);
    acc3 = __builtin_amdgcn_mfma_f32_16x16x32_f16(f3, w3f[3], acc3, 0, 0, 0);
    acc6 = __builtin_amdgcn_mfma_f32_16x16x32_f16(f3, w6f[3], acc6, 0, 0, 0);

    // idx loads for s+2
    int s2 = (s + 2 < S_) ? (s + 2) : (S_ - 1);
    int pi = bj * S_ + s2;
    int tic = c[pi], tisd = sd[pi], tia = a[pi], tict = cshft[pi], tist = sdshft[pi];

    // merged sigmoid: even quads sigmoid(v2) [=g2], odd quads sigmoid(v6) [=g6]
    const float xs  = qodd ? acc6[0] : acc2[0];
    const float g   = fast_sigmoid(xs);
    const float th3 = fast_tanh(acc3[0]);
    const float sdfv = g * th3;               // real on even quads
    if (!qodd) A2[st_off] = (_Float16)sdfv;   // odd rows 4,12 stay zero
    __syncthreads();                          // B1: sdf staged

    // ---- stage 2: W4, W5 on sdf ----
    f16x8 s0 = *(const f16x8*)&A2[rdt[0]];
    f16x8 s1 = *(const f16x8*)&A2[rdt[1]];
    f16x8 s2f = *(const f16x8*)&A2[rdt[2]];
    f16x8 s3 = *(const f16x8*)&A2[rdt[3]];

    acc4[0] = a4v;
    acc5[0] = a5v;
    acc4 = __builtin_amdgcn_mfma_f32_16x16x32_f16(s0, w4f[0], acc4, 0, 0, 0);
    acc5 = __builtin_amdgcn_mfma_f32_16x16x32_f16(s0, w5f[0], acc5, 0, 0, 0);
    acc4 = __builtin_amdgcn_mfma_f32_16x16x32_f16(s1, w4f[1], acc4, 0, 0, 0);
    acc5 = __builtin_amdgcn_mfma_f32_16x16x32_f16(s1, w5f[1], acc5, 0, 0, 0);
    acc4 = __builtin_amdgcn_mfma_f32_16x16x32_f16(s2f, w4f[2], acc4, 0, 0, 0);
    acc5 = __builtin_amdgcn_mfma_f32_16x16x32_f16(s2f, w5f[2], acc5, 0, 0, 0);
    acc4 = __builtin_amdgcn_mfma_f32_16x16x32_f16(s3, w4f[3], acc4, 0, 0, 0);
    acc5 = __builtin_amdgcn_mfma_f32_16x16x32_f16(s3, w5f[3], acc5, 0, 0, 0);

    const float pka = fast_sigmoid(acc4[0]) * fast_tanh(acc5[0]);  // real even quads
    // exchange pka (even quads) <-> g6 (odd quads) within quad pair
    const float send = qodd ? g : pka;
    const float recv = __shfl_xor(send, 16);
    const float gg6  = qodd ? g : recv;
    const float ppka = qodd ? recv : pka;
    const float knew = ppka + gg6 * (kreg - ppka);
    kreg = knew;
    // stage next step's A1: qq' in even-quad rows, k' in odd-quad rows
    A1[st_off] = (_Float16)(qodd ? knew : (knew - ninT));

    // fused logit: dot(target, knew) over e; DPP sum -> lane15 of each quad
    float p = tgt * knew;
    p = DPP_ADD(p, 0x111);
    p = DPP_ADD(p, 0x112);
    p = DPP_ADD(p, 0x114);
    p = DPP_ADD(p, 0x118);
    if (l15 == 15 && !qodd) red[w][j] = p;

    inT = ninT; sd6v = nsd6; a4v = na4; a5v = na5; a6v = na6; tgt = ntg;
    nic = tic; nisd = tisd; nia = tia; nict = tict; nist = tist;

    __syncthreads();                          // B2: A1' + red visible

    if (tid == 0 || tid == 32) {
      const int jj = tid >> 5;
      float logit = 0.f;
      #pragma unroll
      for (int x = 0; x < 8; ++x) logit += red[x][jj];
      out[(blockIdx.x * 2 + jj) * S_ + s] = fast_sigmoid(logit);
    }
  }
}

extern "C" void kernel_launch(void* const* d_in, const int* in_sizes, int n_in,
                              void* d_out, int out_size, void* d_ws, size_t ws_size,
                              hipStream_t stream) {
  const int*   c         = (const int*)  d_in[0];
  const int*   sd        = (const int*)  d_in[1];
  const int*   a         = (const int*)  d_in[2];
  const int*   cshft     = (const int*)  d_in[3];
  const int*   sdshft    = (const int*)  d_in[4];
  const float* c_table   = (const float*)d_in[5];
  const float* sd_table  = (const float*)d_in[6];
  const float* a_table   = (const float*)d_in[7];
  const float* knowledge = (const float*)d_in[8];
  const float* W1 = (const float*)d_in[9];  const float* b1 = (const float*)d_in[10];
  const float* W2 = (const float*)d_in[11]; const float* b2 = (const float*)d_in[12];
  const float* W3 = (const float*)d_in[13]; const float* b3 = (const float*)d_in[14];
  const float* W4 = (const float*)d_in[15]; const float* b4 = (const float*)d_in[16];
  const float* W5 = (const float*)d_in[17]; const float* b5 = (const float*)d_in[18];
  const float* W6 = (const float*)d_in[19]; const float* b6 = (const float*)d_in[20];
  float* ws  = (float*)d_ws;
  float* out = (float*)d_out;
  (void)in_sizes; (void)n_in; (void)out_size; (void)ws_size;

  dimkt_prep<<<1235, 128, 0, stream>>>(c_table, sd_table, a_table,
                                       W1, b1, W4, b4, W5, b5, W6, b6, ws);
  dimkt_scan<<<256, 512, 0, stream>>>(c, sd, a, cshft, sdshft, knowledge,
                                      W2, b2, W3, b3, W4, W5, W6, ws, out);
}